// Round 1
// baseline (408.131 us; speedup 1.0000x reference)
//
#include <hip/hip_runtime.h>

#define DIN 2048
#define NH 16
#define DH 128
#define SEQ 2048
#define BB 2
#define N3 6144
#define MM 4096  // BB*SEQ

typedef __bf16 bf16;
typedef __attribute__((ext_vector_type(8))) __bf16 bf16x8;
typedef __attribute__((ext_vector_type(4))) __bf16 bf16x4;
typedef __attribute__((ext_vector_type(4))) float f32x4;

__device__ __forceinline__ f32x4 mfma16(bf16x8 a, bf16x8 b, f32x4 c) {
  return __builtin_amdgcn_mfma_f32_16x16x32_bf16(a, b, c, 0, 0, 0);
}

__device__ __forceinline__ void async16(const void* g, void* l) {
  __builtin_amdgcn_global_load_lds((const __attribute__((address_space(1))) void*)g,
                                   (__attribute__((address_space(3))) void*)l, 16, 0, 0);
}

// ---------------- dtype sniff ----------------
__global__ void sniff_k(const unsigned short* __restrict__ x, int* __restrict__ flag) {
  __shared__ int cnt;
  if (threadIdx.x == 0) cnt = 0;
  __syncthreads();
  unsigned short u = x[threadIdx.x * 2];
  int e = (u >> 7) & 0xff;
  if (e >= 108 && e <= 140) atomicAdd(&cnt, 1);
  __syncthreads();
  if (threadIdx.x == 0) *flag = (cnt >= 128) ? 1 : 0;
}

// ---------------- casts ----------------
__global__ __launch_bounds__(256) void cast_x_k(const void* __restrict__ in, bf16* __restrict__ out,
                                                const int* __restrict__ flag) {
  size_t i = ((size_t)blockIdx.x * 256 + threadIdx.x) * 8;
  if (*flag) {
    *(bf16x8*)(out + i) = *(const bf16x8*)((const bf16*)in + i);
  } else {
    const float* f = (const float*)in;
    bf16x8 v;
    for (int j = 0; j < 8; j++) v[j] = (bf16)f[i + j];
    *(bf16x8*)(out + i) = v;
  }
}

__global__ __launch_bounds__(256) void cast_wT_k(const void* __restrict__ in, bf16* __restrict__ out,
                                                 const int* __restrict__ flag, int R, int C) {
  __shared__ float t[32][33];
  int c0 = blockIdx.x * 32, r0 = blockIdx.y * 32;
  int tx = threadIdx.x & 31, ty = threadIdx.x >> 5;
  bool isb = *flag != 0;
  for (int j = 0; j < 4; j++) {
    int r = ty + j * 8;
    size_t idx = (size_t)(r0 + r) * C + c0 + tx;
    float v = isb ? (float)((const bf16*)in)[idx] : ((const float*)in)[idx];
    t[r][tx] = v;
  }
  __syncthreads();
  for (int j = 0; j < 4; j++) {
    int c = ty + j * 8;
    out[(size_t)(c0 + c) * R + r0 + tx] = (bf16)t[tx][c];
  }
}

// ---------------- qkv GEMM: 256x256 tile, BK=64, 8-phase counted-vmcnt schedule ----
// 8 waves (2M x 4N), per-wave C = 128x64 (acc[8][4]). LDS 128 KiB: A/B tiles
// 256x64 bf16, double-buffered, 16B-chunk-xor swizzle (chunk c at row r holds
// global chunk c^(r&7)) -> conflict-free ds_read_b128 (verified 0 conflicts).
// Per iteration: 2 K-tiles, 8 phases. Phase = {ds_read subtile || stage 1
// half-tile (2 x global_load_lds)} ; s_barrier ; lgkmcnt(0) ; setprio(1) ;
// 16 MFMA ; setprio(0) ; s_barrier. vmcnt(4) only at phases 4/8: newest needed
// half-tile always has exactly 2 newer half-tiles (4 loads) in flight.
// Staging schedule (t even, buf0=t, buf1=t+1):
//   P1:stA0(t+1)->b1 P2:stA1(t+1)->b1 P3:stB0(t+2)->b0 P4:stB1(t+2)->b0 [vm4]
//   P5:stA0(t+2)->b0 P6:stA1(t+2)->b0 P7:stB0(t+3)->b1 P8:stB1(t+3)->b1 [vm4]
// Each overwritten half was last ds_read >=1 barrier before its stage issue.
// Tail stages wrap (kt&31) into halves that are never read again.
__global__ __launch_bounds__(512) void gemm_qkv_k(const bf16* __restrict__ A, const bf16* __restrict__ BT,
                                                  bf16* __restrict__ Qb, bf16* __restrict__ Kb,
                                                  bf16* __restrict__ Vb) {
  __shared__ __align__(16) bf16 As[2][256 * 64];
  __shared__ __align__(16) bf16 Bs[2][256 * 64];
  const int K = DIN;
  int m0 = blockIdx.y * 256, n0 = blockIdx.x * 256;
  int tid = threadIdx.x, w = tid >> 6, l = tid & 63;
  int l15 = l & 15, quad = l >> 4;
  int wm = (w >> 2) * 128, wn = (w & 3) * 64;
  f32x4 zero = {0.f, 0.f, 0.f, 0.f};
  f32x4 acc[8][4];
  for (int i = 0; i < 8; i++)
    for (int j = 0; j < 4; j++) acc[i][j] = zero;
  // staging: thread t covers row srow (+64 for 2nd load) of the 128-row half,
  // source chunk pre-swizzled so linear DMA lands the xor-swizzled layout.
  int srow = tid >> 3;                 // 0..63
  int gch = (srow & 7) ^ (tid & 7);    // global 16B chunk this lane fetches
  const bf16* Ag = A + (size_t)(m0 + srow) * K + gch * 8;
  const bf16* Bg = BT + (size_t)(n0 + srow) * K + gch * 8;
  int aoff = (wm + l15) * 64;
  int boff = (wn + l15) * 64;
  int cko0 = ((quad) ^ (l15 & 7)) << 3;      // kk=0 chunk offset (elems)
  int cko1 = ((4 + quad) ^ (l15 & 7)) << 3;  // kk=1
  bf16x8 af[4], bf0[4], bf1[4];

#define STA(buf, h, kt)                                          \
  {                                                              \
    const bf16* s_ = Ag + (size_t)(h) * 128 * K + (kt) * 64;     \
    bf16* d_ = &As[buf][((h) * 128 + w * 8) * 64];               \
    async16(s_, d_);                                             \
    async16(s_ + (size_t)64 * K, d_ + 4096);                     \
  }
#define STB(buf, h, kt)                                          \
  {                                                              \
    const bf16* s_ = Bg + (size_t)(h) * 128 * K + (kt) * 64;     \
    bf16* d_ = &Bs[buf][((h) * 128 + w * 8) * 64];               \
    async16(s_, d_);                                             \
    async16(s_ + (size_t)64 * K, d_ + 4096);                     \
  }
#define RDB(buf, BFV, CKO)                                                \
  _Pragma("unroll") for (int j_ = 0; j_ < 4; j_++)                        \
      BFV[j_] = *(const bf16x8*)&Bs[buf][boff + j_ * 1024 + (CKO)];
#define PHASE(buf, IB, BFV, CKO, STG, FEN)                                         \
  {                                                                                \
    _Pragma("unroll") for (int i_ = 0; i_ < 4; i_++)                               \
        af[i_] = *(const bf16x8*)&As[buf][aoff + ((IB) + i_) * 1024 + (CKO)];      \
    STG;                                                                           \
    __builtin_amdgcn_s_barrier();                                                  \
    asm volatile("s_waitcnt lgkmcnt(0)" ::: "memory");                             \
    __builtin_amdgcn_s_setprio(1);                                                 \
    _Pragma("unroll") for (int i_ = 0; i_ < 4; i_++) {                             \
      _Pragma("unroll") for (int j_ = 0; j_ < 4; j_++)                             \
          acc[(IB) + i_][j_] = mfma16(af[i_], BFV[j_], acc[(IB) + i_][j_]);        \
    }                                                                              \
    __builtin_amdgcn_s_setprio(0);                                                 \
    FEN;                                                                           \
    __builtin_amdgcn_s_barrier();                                                  \
  }

  // prologue: queue = [B0(0),B1(0),A0(0),A1(0),B0(1),B1(1)]; vm4 -> tile0 ready
  STB(0, 0, 0);
  STB(0, 1, 0);
  STA(0, 0, 0);
  STA(0, 1, 0);
  STB(1, 0, 1);
  STB(1, 1, 1);
  asm volatile("s_waitcnt vmcnt(4)" ::: "memory");
  __builtin_amdgcn_s_barrier();

  for (int it = 0; it < 16; it++) {
    int t = 2 * it;
    int tp1 = t + 1, tp2 = (t + 2) & 31, tp3 = (t + 3) & 31;
    RDB(0, bf0, cko0);
    PHASE(0, 0, bf0, cko0, STA(1, 0, tp1), );
    RDB(0, bf1, cko1);
    PHASE(0, 0, bf1, cko1, STA(1, 1, tp1), );
    PHASE(0, 4, bf0, cko0, STB(0, 0, tp2), );
    PHASE(0, 4, bf1, cko1, STB(0, 1, tp2), asm volatile("s_waitcnt vmcnt(4)" ::: "memory"));
    RDB(1, bf0, cko0);
    PHASE(1, 0, bf0, cko0, STA(0, 0, tp2), );
    RDB(1, bf1, cko1);
    PHASE(1, 0, bf1, cko1, STA(0, 1, tp2), );
    PHASE(1, 4, bf0, cko0, STB(1, 0, tp3), );
    PHASE(1, 4, bf1, cko1, STB(1, 1, tp3), asm volatile("s_waitcnt vmcnt(4)" ::: "memory"));
  }
  asm volatile("s_waitcnt vmcnt(0)" ::: "memory");  // drain tail DMA before LDS dies
#undef STA
#undef STB
#undef RDB
#undef PHASE

  // epilogue: fused Q/K/V split scatter; K rows carry the 16B-chunk xor swizzle
  for (int j = 0; j < 4; j++) {
    int col = n0 + wn + j * 16 + l15;
    int part = col >> 11, cw = col & 2047;
    int h = cw >> 7, d = cw & 127;
    bf16* dst = (part == 0) ? Qb : ((part == 1) ? Kb : Vb);
    for (int i = 0; i < 8; i++) {
      int mrow = m0 + wm + i * 16 + quad * 4;
      for (int r = 0; r < 4; r++) {
        int m = mrow + r;
        int b = m >> 11, s = m & 2047;
        int dd = (part == 1) ? (((((d >> 3) ^ (s & 7)) << 3)) | (d & 7)) : d;
        dst[(((size_t)(b * NH + h)) * SEQ + s) * DH + dd] = (bf16)acc[i][j][r];
      }
    }
  }
}

// ---------------- RoPE; Q gets DH^-0.5 * log2(e) folded in (scores in log2 domain) ----
__global__ __launch_bounds__(256) void rope_k(bf16* __restrict__ Qb, bf16* __restrict__ Kb) {
  int i = blockIdx.x * 256 + threadIdx.x;  // (bh, s, d2): 32*2048*64
  int d2 = i & 63;
  int s = (i >> 6) & 2047;
  int bh = i >> 17;
  int dl = 2 * d2;
  float invf = expf(-9.210340371976184f * (float)dl * (1.0f / 128.0f));
  float ang = (float)s * invf;
  float sn, cs;
  sincosf(ang, &sn, &cs);
  size_t row = ((size_t)bh * SEQ + s) * DH;
  const float scale = 0.08838834764831845f * 1.4426950408889634f;  // DH^-0.5 * log2(e)
  size_t qb = row + dl;
  float q1 = (float)Qb[qb], q2 = (float)Qb[qb + 1];
  Qb[qb] = (bf16)((q1 * cs - q2 * sn) * scale);
  Qb[qb + 1] = (bf16)((q1 * sn + q2 * cs) * scale);
  size_t kb = row + ((((dl >> 3) ^ (s & 7)) << 3) | (dl & 7));
  float k1 = (float)Kb[kb], k2 = (float)Kb[kb + 1];
  Kb[kb] = (bf16)(k1 * cs - k2 * sn);
  Kb[kb + 1] = (bf16)(k1 * sn + k2 * cs);
}

// ---------------- V transpose: (B,H,S,DH) -> (B,H,DH,S), swizzled within 64-col windows
__global__ __launch_bounds__(256) void transpose_v_k(const bf16* __restrict__ V, bf16* __restrict__ Vt) {
  __shared__ float t[32][33];
  int s0 = blockIdx.x * 32, d0 = blockIdx.y * 32;
  int bh = blockIdx.z;
  const bf16* Vp = V + (size_t)bh * SEQ * DH;
  bf16* Vo = Vt + (size_t)bh * DH * SEQ;
  int tx = threadIdx.x & 31, ty = threadIdx.x >> 5;
  for (int j = 0; j < 4; j++)
    t[ty + j * 8][tx] = (float)Vp[(size_t)(s0 + ty + j * 8) * DH + d0 + tx];
  __syncthreads();
  for (int j = 0; j < 4; j++) {
    int dh = d0 + ty + j * 8;
    int s = s0 + tx;
    int sl = s & 63;
    int col = (s & ~63) | ((((sl >> 3) ^ (dh & 7)) << 3) | (sl & 7));
    Vo[(size_t)dh * SEQ + col] = (bf16)t[tx][ty + j * 8];
  }
}

// ---------------- flash attention v4 ----------------
// Q-tile 64 (4 waves x 16 q-rows), K-tile 64 double-buffered; 73.5 KB LDS ->
// 2 blocks/CU = 2 waves/SIMD. grid (32 bh, 16 slots), slot does Q-tiles
// (31-slot, slot) = exactly 33 k-iters per block.
__global__ __launch_bounds__(256, 2) void attn_k(const bf16* __restrict__ Qb, const bf16* __restrict__ Kb,
                                                 const bf16* __restrict__ Vt, bf16* __restrict__ Yb) {
  __shared__ __align__(16) bf16 Ks[2][64 * 128];
  __shared__ __align__(16) bf16 Vs[2][128 * 64];
  __shared__ __align__(16) bf16 Pl[4][16 * 76];
  int bh = blockIdx.x;
  int slot = blockIdx.y;
  int w = threadIdx.x >> 6, l = threadIdx.x & 63;
  int l15 = l & 15, quad = l >> 4;
  const bf16* Qp = Qb + (size_t)bh * SEQ * DH;
  const bf16* Kp = Kb + (size_t)bh * SEQ * DH;
  const bf16* Vp = Vt + (size_t)bh * DH * SEQ;
  int b = bh >> 4, h = bh & 15;
  f32x4 zero = {0.f, 0.f, 0.f, 0.f};
  bf16* P = &Pl[w][0];

  auto stage = [&](int it, int buf) {
    const char* gk = (const char*)Kp + (size_t)it * 16384 + w * 4096 + l * 16;
    char* lk = (char*)&Ks[buf][0] + w * 4096;
    for (int i = 0; i < 4; i++) async16(gk + i * 1024, lk + i * 1024);
    const char* gv = (const char*)Vp + (size_t)it * 128 + (size_t)(w * 32 + (l >> 3)) * (SEQ * 2) + (l & 7) * 16;
    char* lv = (char*)&Vs[buf][0] + w * 32 * 128;
    for (int i = 0; i < 4; i++) async16(gv + (size_t)i * 8 * (SEQ * 2), lv + i * 1024);
  };

  int tiles[2] = {31 - slot, slot};
  for (int half = 0; half < 2; half++) {
    int tile = tiles[half];
    int qw = tile * 64 + w * 16;  // this wave's 16 q rows
    bf16x8 qf[4];
    for (int kc = 0; kc < 4; kc++)
      qf[kc] = *(const bf16x8*)&Qp[(size_t)(qw + l15) * DH + kc * 32 + quad * 8];
    f32x4 o[8];
    for (int ns = 0; ns < 8; ns++) o[ns] = zero;
    float mprev = -1e30f, lsum = 0.f;
    int nkt = tile + 1;

    stage(0, 0);
    __syncthreads();
    for (int it = 0; it < nkt; it++) {
      int buf = it & 1;
      if (it + 1 < nkt) stage(it + 1, buf ^ 1);
      int k0 = it * 64;
      // S^T = K(row) x Q(col=l15=q)
      f32x4 st[4];
      for (int ns = 0; ns < 4; ns++) st[ns] = zero;
      for (int kc = 0; kc < 4; kc++)
        for (int ns = 0; ns < 4; ns++) {
          bf16x8 kf = *(const bf16x8*)&Ks[buf][(ns * 16 + l15) * 128 + (((kc * 4 + quad) ^ (l15 & 7)) << 3)];
          st[ns] = mfma16(kf, qf[kc], st[ns]);
        }
      int qq = qw + l15;
      if (k0 + 63 > qw) {  // diagonal tile: mask k > q
        for (int ns = 0; ns < 4; ns++) {
          int kk = k0 + ns * 16 + quad * 4;
          for (int r = 0; r < 4; r++)
            if (kk + r > qq) st[ns][r] = -1e30f;
        }
      }
      float pm = -1e30f;
      for (int ns = 0; ns < 4; ns++)
        for (int r = 0; r < 4; r++) pm = fmaxf(pm, st[ns][r]);
      pm = fmaxf(pm, __shfl_xor(pm, 16, 64));
      pm = fmaxf(pm, __shfl_xor(pm, 32, 64));
      float mnew = fmaxf(mprev, pm);
      float al = exp2f(mprev - mnew);
      mprev = mnew;
      float ps = 0.f;
      for (int ns = 0; ns < 4; ns++)
        for (int r = 0; r < 4; r++) {
          float e = exp2f(st[ns][r] - mnew);
          st[ns][r] = e;
          ps += e;
        }
      ps += __shfl_xor(ps, 16, 64);
      ps += __shfl_xor(ps, 32, 64);
      lsum = lsum * al + ps;
      for (int ns = 0; ns < 8; ns++) o[ns] *= al;
      // P^T (C-layout) -> P[q][k] rows: lane holds k=quad*4..+3 contiguous -> b64 writes
      for (int ns = 0; ns < 4; ns++) {
        bf16x4 pk;
        for (int r = 0; r < 4; r++) pk[r] = (bf16)st[ns][r];
        *(bf16x4*)&P[l15 * 76 + ns * 16 + quad * 4] = pk;
      }
      asm volatile("s_waitcnt lgkmcnt(0)" ::: "memory");
      bf16x8 pa[2];
      for (int kc = 0; kc < 2; kc++)
        pa[kc] = *(const bf16x8*)&P[l15 * 76 + kc * 32 + quad * 8];
      for (int ns = 0; ns < 8; ns++)
        for (int kc = 0; kc < 2; kc++) {
          bf16x8 vf = *(const bf16x8*)&Vs[buf][(ns * 16 + l15) * 64 + (((kc * 4 + quad) ^ (l15 & 7)) << 3)];
          o[ns] = mfma16(vf, pa[kc], o[ns]);  // O^T: col=l15=q
        }
      __syncthreads();
    }
    // epilogue: O^T col=l15=q, row(within ns)=quad*4+r -> d = ns*16+quad*4+r
    float inv = 1.0f / lsum;
    int q = qw + l15;
    size_t base = ((size_t)(b * SEQ + q)) * DIN + h * DH + quad * 4;
    for (int ns = 0; ns < 8; ns++) {
      bf16x4 pk;
      for (int r = 0; r < 4; r++) pk[r] = (bf16)(o[ns][r] * inv);
      *(bf16x4*)&Yb[base + ns * 16] = pk;
    }
  }
}

// ---------------- proj GEMM (BK=64, xor-swizzled LDS chunks) ----------------
__global__ __launch_bounds__(256) void gemm_proj_k(const bf16* __restrict__ A, const bf16* __restrict__ BT,
                                                   void* __restrict__ out, const int* __restrict__ flag) {
  __shared__ __align__(16) bf16 As[128 * 64];
  __shared__ __align__(16) bf16 Bs[128 * 64];
  const int K = DIN;
  int m0 = blockIdx.y * 128, n0 = blockIdx.x * 128;
  int tid = threadIdx.x, w = tid >> 6, l = tid & 63;
  int l15 = l & 15, quad = l >> 4;
  int wm = (w & 1) * 64, wn = (w >> 1) * 64;
  bool obf = *flag != 0;
  f32x4 zero = {0.f, 0.f, 0.f, 0.f};
  f32x4 acc[4][4];
  for (int i = 0; i < 4; i++)
    for (int j = 0; j < 4; j++) acc[i][j] = zero;
  int gch = (l & 7) ^ (l >> 3);
  const bf16* Ag = A + (size_t)(m0 + w * 32 + (l >> 3)) * K + gch * 8;
  const bf16* Bg = BT + (size_t)(n0 + w * 32 + (l >> 3)) * K + gch * 8;
  bf16* AsW = As + w * 2048;
  bf16* BsW = Bs + w * 2048;
  for (int k0 = 0; k0 < K; k0 += 64) {
    __syncthreads();
    for (int j = 0; j < 4; j++) async16(Ag + k0 + (size_t)j * 8 * K, AsW + j * 512);
    for (int j = 0; j < 4; j++) async16(Bg + k0 + (size_t)j * 8 * K, BsW + j * 512);
    __syncthreads();
    for (int kk = 0; kk < 2; kk++) {
      bf16x8 af[4], bfv[4];
      for (int i = 0; i < 4; i++)
        af[i] = *(const bf16x8*)&As[(wm + i * 16 + l15) * 64 + (((kk * 4 + quad) ^ (l15 & 7)) << 3)];
      for (int j = 0; j < 4; j++)
        bfv[j] = *(const bf16x8*)&Bs[(wn + j * 16 + l15) * 64 + (((kk * 4 + quad) ^ (l15 & 7)) << 3)];
      for (int i = 0; i < 4; i++)
        for (int j = 0; j < 4; j++) acc[i][j] = mfma16(af[i], bfv[j], acc[i][j]);
    }
  }
  for (int j = 0; j < 4; j++) {
    int col = n0 + wn + j * 16 + l15;
    for (int i = 0; i < 4; i++) {
      int mrow = m0 + wm + i * 16 + quad * 4;
      for (int r = 0; r < 4; r++) {
        size_t idx = (size_t)(mrow + r) * DIN + col;
        float v = acc[i][j][r];
        if (obf)
          ((bf16*)out)[idx] = (bf16)v;
        else
          ((float*)out)[idx] = v;
      }
    }
  }
}

extern "C" void kernel_launch(void* const* d_in, const int* in_sizes, int n_in,
                              void* d_out, int out_size, void* d_ws, size_t ws_size,
                              hipStream_t stream) {
  char* ws = (char*)d_ws;
  int* flag = (int*)ws;
  bf16* Xb = (bf16*)(ws + 256);                                  // 16 MiB, aliased with Yb
  bf16* WqkvT = (bf16*)(ws + 256 + 16777216);                    // 24 MiB
  bf16* WprojT = (bf16*)(ws + 256 + 16777216 + 25165824);        // 8 MiB
  bf16* Qb = (bf16*)(ws + 256 + 16777216 + 25165824 + 8388608);  // 16 MiB each
  bf16* Kb = Qb + (size_t)MM * DIN;
  bf16* Vb = Kb + (size_t)MM * DIN;
  bf16* Vt = Vb + (size_t)MM * DIN;
  bf16* Yb = Xb;  // Xb dead after gemm_qkv

  sniff_k<<<1, 256, 0, stream>>>((const unsigned short*)d_in[0], flag);
  cast_x_k<<<4096, 256, 0, stream>>>(d_in[0], Xb, flag);
  cast_wT_k<<<dim3(192, 64), 256, 0, stream>>>(d_in[1], WqkvT, flag, DIN, N3);
  cast_wT_k<<<dim3(64, 64), 256, 0, stream>>>(d_in[2], WprojT, flag, DIN, DIN);
  gemm_qkv_k<<<dim3(24, 16), 512, 0, stream>>>(Xb, WqkvT, Qb, Kb, Vb);
  rope_k<<<16384, 256, 0, stream>>>(Qb, Kb);
  transpose_v_k<<<dim3(64, 4, 32), 256, 0, stream>>>(Vb, Vt);
  attn_k<<<dim3(32, 16), 256, 0, stream>>>(Qb, Kb, Vt, Yb);
  gemm_proj_k<<<dim3(16, 32), 256, 0, stream>>>(Yb, WprojT, d_out, flag);
}

// Round 2
// 401.329 us; speedup vs baseline: 1.0169x; 1.0169x over previous
//
#include <hip/hip_runtime.h>

#define DIN 2048
#define NH 16
#define DH 128
#define SEQ 2048
#define BB 2
#define N3 6144
#define MM 4096  // BB*SEQ

typedef __bf16 bf16;
typedef __attribute__((ext_vector_type(8))) __bf16 bf16x8;
typedef __attribute__((ext_vector_type(4))) __bf16 bf16x4;
typedef __attribute__((ext_vector_type(4))) float f32x4;

__device__ __forceinline__ f32x4 mfma16(bf16x8 a, bf16x8 b, f32x4 c) {
  return __builtin_amdgcn_mfma_f32_16x16x32_bf16(a, b, c, 0, 0, 0);
}

__device__ __forceinline__ void async16(const void* g, void* l) {
  __builtin_amdgcn_global_load_lds((const __attribute__((address_space(1))) void*)g,
                                   (__attribute__((address_space(3))) void*)l, 16, 0, 0);
}

// ---------------- dtype sniff ----------------
__global__ void sniff_k(const unsigned short* __restrict__ x, int* __restrict__ flag) {
  __shared__ int cnt;
  if (threadIdx.x == 0) cnt = 0;
  __syncthreads();
  unsigned short u = x[threadIdx.x * 2];
  int e = (u >> 7) & 0xff;
  if (e >= 108 && e <= 140) atomicAdd(&cnt, 1);
  __syncthreads();
  if (threadIdx.x == 0) *flag = (cnt >= 128) ? 1 : 0;
}

// ---------------- casts ----------------
__global__ __launch_bounds__(256) void cast_x_k(const void* __restrict__ in, bf16* __restrict__ out,
                                                const int* __restrict__ flag) {
  size_t i = ((size_t)blockIdx.x * 256 + threadIdx.x) * 8;
  if (*flag) {
    *(bf16x8*)(out + i) = *(const bf16x8*)((const bf16*)in + i);
  } else {
    const float* f = (const float*)in;
    bf16x8 v;
    for (int j = 0; j < 8; j++) v[j] = (bf16)f[i + j];
    *(bf16x8*)(out + i) = v;
  }
}

__global__ __launch_bounds__(256) void cast_wT_k(const void* __restrict__ in, bf16* __restrict__ out,
                                                 const int* __restrict__ flag, int R, int C) {
  __shared__ float t[32][33];
  int c0 = blockIdx.x * 32, r0 = blockIdx.y * 32;
  int tx = threadIdx.x & 31, ty = threadIdx.x >> 5;
  bool isb = *flag != 0;
  for (int j = 0; j < 4; j++) {
    int r = ty + j * 8;
    size_t idx = (size_t)(r0 + r) * C + c0 + tx;
    float v = isb ? (float)((const bf16*)in)[idx] : ((const float*)in)[idx];
    t[r][tx] = v;
  }
  __syncthreads();
  for (int j = 0; j < 4; j++) {
    int c = ty + j * 8;
    out[(size_t)(c0 + c) * R + r0 + tx] = (bf16)t[tx][c];
  }
}

// ---------------- qkv GEMM: 128x256 tile, BK=64, 4-phase counted-vmcnt schedule ----
// 768 blocks = exactly 3.0 rounds on 256 CUs (round-1's 384-block 256^2 config had
// a 1.5-round tail -> 75% ceiling). 8 waves (2M x 4N), per-wave 64x64 (acc[4][4]).
// LDS 96 KiB: A 2x128x64, B 2x256x64, chunk-xor swizzled (chunk c at row r holds
// global chunk c^(r&7)) -> 2-way-free ds_read_b128.
// Per iteration: 2 K-tiles T0=2i (buf0), T1=2i+1 (buf1); 4 phases of 16 MFMA.
// All 16 frags of a tile are register-cached at its first phase, freeing the
// buffer one barrier later. 12 loads/thread/iter spread 3 per phase:
//   P1: read T0 frags | S1=B(T1)u123   | bar lgkm0 mfma(k0) bar
//   P2: S2=A(T0+2)+B(T0+2)u0          | bar mfma(k1) vmcnt(3) bar   <- T1 ready
//   P3: read T1 frags | S3=B(T0+2)u123 | bar lgkm0 mfma(k0) bar
//   P4: S4=A(T1+3->buf1)+B u0         | bar mfma(k1) vmcnt(3) bar   <- T0+2 ready
// vmcnt(3) always before an end-barrier (cross-wave publish); every waited load
// is >=2 phases (~1200cy > 900cy HBM) old. Each restage issues >=1 barrier after
// its buffer tenant's reads completed. Tail kt wraps (&31) into dead buffers.
__global__ __launch_bounds__(512, 2) void gemm_qkv_k(const bf16* __restrict__ A, const bf16* __restrict__ BT,
                                                     bf16* __restrict__ Qb, bf16* __restrict__ Kb,
                                                     bf16* __restrict__ Vb) {
  __shared__ __align__(16) bf16 As[2][128 * 64];
  __shared__ __align__(16) bf16 Bs[2][256 * 64];
  const int K = DIN;
  int m0 = blockIdx.y * 128, n0 = blockIdx.x * 256;
  int tid = threadIdx.x, w = tid >> 6, l = tid & 63;
  int l15 = l & 15, quad = l >> 4;
  int wm = (w >> 2) * 64, wn = (w & 3) * 64;
  f32x4 zero = {0.f, 0.f, 0.f, 0.f};
  f32x4 acc[4][4];
  for (int i = 0; i < 4; i++)
    for (int j = 0; j < 4; j++) acc[i][j] = zero;
  // staging: thread covers row srow (+64/128/192 for later units), source chunk
  // pre-swizzled so the linear DMA lands the xor-swizzled layout.
  int srow = tid >> 3;               // 0..63
  int gch = (srow & 7) ^ (tid & 7);  // global 16B chunk this lane fetches
  const bf16* Ag = A + (size_t)(m0 + srow) * K + gch * 8;
  const bf16* Bg = BT + (size_t)(n0 + srow) * K + gch * 8;
  int aoff = (wm + l15) * 64;
  int boff = (wn + l15) * 64;
  int ck0 = ((quad) ^ (l15 & 7)) << 3;      // kk=0 chunk offset (elems)
  int ck1 = ((4 + quad) ^ (l15 & 7)) << 3;  // kk=1
  bf16x8 a0f[4], a1f[4], b0f[4], b1f[4];

#define STA(buf, kt)                                   \
  {                                                    \
    const bf16* s_ = Ag + (kt) * 64;                   \
    async16(s_, &As[buf][w * 512]);                    \
    async16(s_ + (size_t)64 * K, &As[buf][w * 512 + 4096]); \
  }
#define STB(buf, kt, u)                                                  \
  {                                                                      \
    async16(Bg + (kt) * 64 + (size_t)(u) * 64 * K,                       \
            &Bs[buf][(u) * 4096 + w * 512]);                             \
  }
#define RF(buf)                                                           \
  {                                                                       \
    _Pragma("unroll") for (int q_ = 0; q_ < 4; q_++) {                    \
      a0f[q_] = *(const bf16x8*)&As[buf][aoff + q_ * 1024 + ck0];         \
      a1f[q_] = *(const bf16x8*)&As[buf][aoff + q_ * 1024 + ck1];         \
      b0f[q_] = *(const bf16x8*)&Bs[buf][boff + q_ * 1024 + ck0];         \
      b1f[q_] = *(const bf16x8*)&Bs[buf][boff + q_ * 1024 + ck1];         \
    }                                                                     \
  }
#define MF16(AF, BF)                                                      \
  {                                                                       \
    _Pragma("unroll") for (int i_ = 0; i_ < 4; i_++) {                    \
      _Pragma("unroll") for (int j_ = 0; j_ < 4; j_++)                    \
          acc[i_][j_] = mfma16(AF[i_], BF[j_], acc[i_][j_]);              \
    }                                                                     \
  }

  // prologue: tile0 fully (6 loads) + A(1)+B(1,u0) (3 loads); wait tile0, publish.
  STA(0, 0);
  STB(0, 0, 0);
  STB(0, 0, 1);
  STB(0, 0, 2);
  STB(0, 0, 3);
  STA(1, 1);
  STB(1, 1, 0);
  asm volatile("s_waitcnt vmcnt(3)" ::: "memory");
  __builtin_amdgcn_s_barrier();

#pragma unroll 1
  for (int it = 0; it < 16; it++) {
    int t = 2 * it;
    int kt2 = (t + 2) & 31, kt3 = (t + 3) & 31;
    // P1
    RF(0);
    STB(1, t + 1, 1);
    STB(1, t + 1, 2);
    STB(1, t + 1, 3);
    __builtin_amdgcn_s_barrier();
    asm volatile("s_waitcnt lgkmcnt(0)" ::: "memory");
    __builtin_amdgcn_sched_barrier(0);
    __builtin_amdgcn_s_setprio(1);
    MF16(a0f, b0f);
    __builtin_amdgcn_s_setprio(0);
    __builtin_amdgcn_s_barrier();
    // P2
    STA(0, kt2);
    STB(0, kt2, 0);
    __builtin_amdgcn_s_barrier();
    __builtin_amdgcn_s_setprio(1);
    MF16(a1f, b1f);
    __builtin_amdgcn_s_setprio(0);
    asm volatile("s_waitcnt vmcnt(3)" ::: "memory");
    __builtin_amdgcn_s_barrier();
    // P3
    RF(1);
    STB(0, kt2, 1);
    STB(0, kt2, 2);
    STB(0, kt2, 3);
    __builtin_amdgcn_s_barrier();
    asm volatile("s_waitcnt lgkmcnt(0)" ::: "memory");
    __builtin_amdgcn_sched_barrier(0);
    __builtin_amdgcn_s_setprio(1);
    MF16(a0f, b0f);
    __builtin_amdgcn_s_setprio(0);
    __builtin_amdgcn_s_barrier();
    // P4
    STA(1, kt3);
    STB(1, kt3, 0);
    __builtin_amdgcn_s_barrier();
    __builtin_amdgcn_s_setprio(1);
    MF16(a1f, b1f);
    __builtin_amdgcn_s_setprio(0);
    asm volatile("s_waitcnt vmcnt(3)" ::: "memory");
    __builtin_amdgcn_s_barrier();
  }
  asm volatile("s_waitcnt vmcnt(0)" ::: "memory");  // drain tail DMA before LDS dies
#undef STA
#undef STB
#undef RF
#undef MF16

  // epilogue: fused Q/K/V split scatter; K rows carry the 16B-chunk xor swizzle
  for (int j = 0; j < 4; j++) {
    int col = n0 + wn + j * 16 + l15;
    int part = col >> 11, cw = col & 2047;
    int h = cw >> 7, d = cw & 127;
    bf16* dst = (part == 0) ? Qb : ((part == 1) ? Kb : Vb);
    for (int i = 0; i < 4; i++) {
      int mrow = m0 + wm + i * 16 + quad * 4;
      for (int r = 0; r < 4; r++) {
        int m = mrow + r;
        int b = m >> 11, s = m & 2047;
        int dd = (part == 1) ? (((((d >> 3) ^ (s & 7)) << 3)) | (d & 7)) : d;
        dst[(((size_t)(b * NH + h)) * SEQ + s) * DH + dd] = (bf16)acc[i][j][r];
      }
    }
  }
}

// ---------------- RoPE; Q gets DH^-0.5 * log2(e) folded in (scores in log2 domain) ----
__global__ __launch_bounds__(256) void rope_k(bf16* __restrict__ Qb, bf16* __restrict__ Kb) {
  int i = blockIdx.x * 256 + threadIdx.x;  // (bh, s, d2): 32*2048*64
  int d2 = i & 63;
  int s = (i >> 6) & 2047;
  int bh = i >> 17;
  int dl = 2 * d2;
  float invf = expf(-9.210340371976184f * (float)dl * (1.0f / 128.0f));
  float ang = (float)s * invf;
  float sn, cs;
  sincosf(ang, &sn, &cs);
  size_t row = ((size_t)bh * SEQ + s) * DH;
  const float scale = 0.08838834764831845f * 1.4426950408889634f;  // DH^-0.5 * log2(e)
  size_t qb = row + dl;
  float q1 = (float)Qb[qb], q2 = (float)Qb[qb + 1];
  Qb[qb] = (bf16)((q1 * cs - q2 * sn) * scale);
  Qb[qb + 1] = (bf16)((q1 * sn + q2 * cs) * scale);
  size_t kb = row + ((((dl >> 3) ^ (s & 7)) << 3) | (dl & 7));
  float k1 = (float)Kb[kb], k2 = (float)Kb[kb + 1];
  Kb[kb] = (bf16)(k1 * cs - k2 * sn);
  Kb[kb + 1] = (bf16)(k1 * sn + k2 * cs);
}

// ---------------- V transpose: (B,H,S,DH) -> (B,H,DH,S), swizzled within 64-col windows
__global__ __launch_bounds__(256) void transpose_v_k(const bf16* __restrict__ V, bf16* __restrict__ Vt) {
  __shared__ float t[32][33];
  int s0 = blockIdx.x * 32, d0 = blockIdx.y * 32;
  int bh = blockIdx.z;
  const bf16* Vp = V + (size_t)bh * SEQ * DH;
  bf16* Vo = Vt + (size_t)bh * DH * SEQ;
  int tx = threadIdx.x & 31, ty = threadIdx.x >> 5;
  for (int j = 0; j < 4; j++)
    t[ty + j * 8][tx] = (float)Vp[(size_t)(s0 + ty + j * 8) * DH + d0 + tx];
  __syncthreads();
  for (int j = 0; j < 4; j++) {
    int dh = d0 + ty + j * 8;
    int s = s0 + tx;
    int sl = s & 63;
    int col = (s & ~63) | ((((sl >> 3) ^ (dh & 7)) << 3) | (sl & 7));
    Vo[(size_t)dh * SEQ + col] = (bf16)t[tx][ty + j * 8];
  }
}

// ---------------- flash attention v4 ----------------
// Q-tile 64 (4 waves x 16 q-rows), K-tile 64 double-buffered; 73.5 KB LDS ->
// 2 blocks/CU = 2 waves/SIMD. grid (32 bh, 16 slots), slot does Q-tiles
// (31-slot, slot) = exactly 33 k-iters per block.
__global__ __launch_bounds__(256, 2) void attn_k(const bf16* __restrict__ Qb, const bf16* __restrict__ Kb,
                                                 const bf16* __restrict__ Vt, bf16* __restrict__ Yb) {
  __shared__ __align__(16) bf16 Ks[2][64 * 128];
  __shared__ __align__(16) bf16 Vs[2][128 * 64];
  __shared__ __align__(16) bf16 Pl[4][16 * 76];
  int bh = blockIdx.x;
  int slot = blockIdx.y;
  int w = threadIdx.x >> 6, l = threadIdx.x & 63;
  int l15 = l & 15, quad = l >> 4;
  const bf16* Qp = Qb + (size_t)bh * SEQ * DH;
  const bf16* Kp = Kb + (size_t)bh * SEQ * DH;
  const bf16* Vp = Vt + (size_t)bh * DH * SEQ;
  int b = bh >> 4, h = bh & 15;
  f32x4 zero = {0.f, 0.f, 0.f, 0.f};
  bf16* P = &Pl[w][0];

  auto stage = [&](int it, int buf) {
    const char* gk = (const char*)Kp + (size_t)it * 16384 + w * 4096 + l * 16;
    char* lk = (char*)&Ks[buf][0] + w * 4096;
    for (int i = 0; i < 4; i++) async16(gk + i * 1024, lk + i * 1024);
    const char* gv = (const char*)Vp + (size_t)it * 128 + (size_t)(w * 32 + (l >> 3)) * (SEQ * 2) + (l & 7) * 16;
    char* lv = (char*)&Vs[buf][0] + w * 32 * 128;
    for (int i = 0; i < 4; i++) async16(gv + (size_t)i * 8 * (SEQ * 2), lv + i * 1024);
  };

  int tiles[2] = {31 - slot, slot};
  for (int half = 0; half < 2; half++) {
    int tile = tiles[half];
    int qw = tile * 64 + w * 16;  // this wave's 16 q rows
    bf16x8 qf[4];
    for (int kc = 0; kc < 4; kc++)
      qf[kc] = *(const bf16x8*)&Qp[(size_t)(qw + l15) * DH + kc * 32 + quad * 8];
    f32x4 o[8];
    for (int ns = 0; ns < 8; ns++) o[ns] = zero;
    float mprev = -1e30f, lsum = 0.f;
    int nkt = tile + 1;

    stage(0, 0);
    __syncthreads();
    for (int it = 0; it < nkt; it++) {
      int buf = it & 1;
      if (it + 1 < nkt) stage(it + 1, buf ^ 1);
      int k0 = it * 64;
      // S^T = K(row) x Q(col=l15=q)
      f32x4 st[4];
      for (int ns = 0; ns < 4; ns++) st[ns] = zero;
      for (int kc = 0; kc < 4; kc++)
        for (int ns = 0; ns < 4; ns++) {
          bf16x8 kf = *(const bf16x8*)&Ks[buf][(ns * 16 + l15) * 128 + (((kc * 4 + quad) ^ (l15 & 7)) << 3)];
          st[ns] = mfma16(kf, qf[kc], st[ns]);
        }
      int qq = qw + l15;
      if (k0 + 63 > qw) {  // diagonal tile: mask k > q
        for (int ns = 0; ns < 4; ns++) {
          int kk = k0 + ns * 16 + quad * 4;
          for (int r = 0; r < 4; r++)
            if (kk + r > qq) st[ns][r] = -1e30f;
        }
      }
      float pm = -1e30f;
      for (int ns = 0; ns < 4; ns++)
        for (int r = 0; r < 4; r++) pm = fmaxf(pm, st[ns][r]);
      pm = fmaxf(pm, __shfl_xor(pm, 16, 64));
      pm = fmaxf(pm, __shfl_xor(pm, 32, 64));
      float mnew = fmaxf(mprev, pm);
      float al = exp2f(mprev - mnew);
      mprev = mnew;
      float ps = 0.f;
      for (int ns = 0; ns < 4; ns++)
        for (int r = 0; r < 4; r++) {
          float e = exp2f(st[ns][r] - mnew);
          st[ns][r] = e;
          ps += e;
        }
      ps += __shfl_xor(ps, 16, 64);
      ps += __shfl_xor(ps, 32, 64);
      lsum = lsum * al + ps;
      for (int ns = 0; ns < 8; ns++) o[ns] *= al;
      // P^T (C-layout) -> P[q][k] rows: lane holds k=quad*4..+3 contiguous -> b64 writes
      for (int ns = 0; ns < 4; ns++) {
        bf16x4 pk;
        for (int r = 0; r < 4; r++) pk[r] = (bf16)st[ns][r];
        *(bf16x4*)&P[l15 * 76 + ns * 16 + quad * 4] = pk;
      }
      asm volatile("s_waitcnt lgkmcnt(0)" ::: "memory");
      bf16x8 pa[2];
      for (int kc = 0; kc < 2; kc++)
        pa[kc] = *(const bf16x8*)&P[l15 * 76 + kc * 32 + quad * 8];
      for (int ns = 0; ns < 8; ns++)
        for (int kc = 0; kc < 2; kc++) {
          bf16x8 vf = *(const bf16x8*)&Vs[buf][(ns * 16 + l15) * 64 + (((kc * 4 + quad) ^ (l15 & 7)) << 3)];
          o[ns] = mfma16(vf, pa[kc], o[ns]);  // O^T: col=l15=q
        }
      __syncthreads();
    }
    // epilogue: O^T col=l15=q, row(within ns)=quad*4+r -> d = ns*16+quad*4+r
    float inv = 1.0f / lsum;
    int q = qw + l15;
    size_t base = ((size_t)(b * SEQ + q)) * DIN + h * DH + quad * 4;
    for (int ns = 0; ns < 8; ns++) {
      bf16x4 pk;
      for (int r = 0; r < 4; r++) pk[r] = (bf16)(o[ns][r] * inv);
      *(bf16x4*)&Yb[base + ns * 16] = pk;
    }
  }
}

// ---------------- proj GEMM (BK=64, xor-swizzled LDS chunks) ----------------
__global__ __launch_bounds__(256) void gemm_proj_k(const bf16* __restrict__ A, const bf16* __restrict__ BT,
                                                   void* __restrict__ out, const int* __restrict__ flag) {
  __shared__ __align__(16) bf16 As[128 * 64];
  __shared__ __align__(16) bf16 Bs[128 * 64];
  const int K = DIN;
  int m0 = blockIdx.y * 128, n0 = blockIdx.x * 128;
  int tid = threadIdx.x, w = tid >> 6, l = tid & 63;
  int l15 = l & 15, quad = l >> 4;
  int wm = (w & 1) * 64, wn = (w >> 1) * 64;
  bool obf = *flag != 0;
  f32x4 zero = {0.f, 0.f, 0.f, 0.f};
  f32x4 acc[4][4];
  for (int i = 0; i < 4; i++)
    for (int j = 0; j < 4; j++) acc[i][j] = zero;
  int gch = (l & 7) ^ (l >> 3);
  const bf16* Ag = A + (size_t)(m0 + w * 32 + (l >> 3)) * K + gch * 8;
  const bf16* Bg = BT + (size_t)(n0 + w * 32 + (l >> 3)) * K + gch * 8;
  bf16* AsW = As + w * 2048;
  bf16* BsW = Bs + w * 2048;
  for (int k0 = 0; k0 < K; k0 += 64) {
    __syncthreads();
    for (int j = 0; j < 4; j++) async16(Ag + k0 + (size_t)j * 8 * K, AsW + j * 512);
    for (int j = 0; j < 4; j++) async16(Bg + k0 + (size_t)j * 8 * K, BsW + j * 512);
    __syncthreads();
    for (int kk = 0; kk < 2; kk++) {
      bf16x8 af[4], bfv[4];
      for (int i = 0; i < 4; i++)
        af[i] = *(const bf16x8*)&As[(wm + i * 16 + l15) * 64 + (((kk * 4 + quad) ^ (l15 & 7)) << 3)];
      for (int j = 0; j < 4; j++)
        bfv[j] = *(const bf16x8*)&Bs[(wn + j * 16 + l15) * 64 + (((kk * 4 + quad) ^ (l15 & 7)) << 3)];
      for (int i = 0; i < 4; i++)
        for (int j = 0; j < 4; j++) acc[i][j] = mfma16(af[i], bfv[j], acc[i][j]);
    }
  }
  for (int j = 0; j < 4; j++) {
    int col = n0 + wn + j * 16 + l15;
    for (int i = 0; i < 4; i++) {
      int mrow = m0 + wm + i * 16 + quad * 4;
      for (int r = 0; r < 4; r++) {
        size_t idx = (size_t)(mrow + r) * DIN + col;
        float v = acc[i][j][r];
        if (obf)
          ((bf16*)out)[idx] = (bf16)v;
        else
          ((float*)out)[idx] = v;
      }
    }
  }
}

extern "C" void kernel_launch(void* const* d_in, const int* in_sizes, int n_in,
                              void* d_out, int out_size, void* d_ws, size_t ws_size,
                              hipStream_t stream) {
  char* ws = (char*)d_ws;
  int* flag = (int*)ws;
  bf16* Xb = (bf16*)(ws + 256);                                  // 16 MiB, aliased with Yb
  bf16* WqkvT = (bf16*)(ws + 256 + 16777216);                    // 24 MiB
  bf16* WprojT = (bf16*)(ws + 256 + 16777216 + 25165824);        // 8 MiB
  bf16* Qb = (bf16*)(ws + 256 + 16777216 + 25165824 + 8388608);  // 16 MiB each
  bf16* Kb = Qb + (size_t)MM * DIN;
  bf16* Vb = Kb + (size_t)MM * DIN;
  bf16* Vt = Vb + (size_t)MM * DIN;
  bf16* Yb = Xb;  // Xb dead after gemm_qkv

  sniff_k<<<1, 256, 0, stream>>>((const unsigned short*)d_in[0], flag);
  cast_x_k<<<4096, 256, 0, stream>>>(d_in[0], Xb, flag);
  cast_wT_k<<<dim3(192, 64), 256, 0, stream>>>(d_in[1], WqkvT, flag, DIN, N3);
  cast_wT_k<<<dim3(64, 64), 256, 0, stream>>>(d_in[2], WprojT, flag, DIN, DIN);
  gemm_qkv_k<<<dim3(24, 32), 512, 0, stream>>>(Xb, WqkvT, Qb, Kb, Vb);
  rope_k<<<16384, 256, 0, stream>>>(Qb, Kb);
  transpose_v_k<<<dim3(64, 4, 32), 256, 0, stream>>>(Vb, Vt);
  attn_k<<<dim3(32, 16), 256, 0, stream>>>(Qb, Kb, Vt, Yb);
  gemm_proj_k<<<dim3(16, 32), 256, 0, stream>>>(Yb, WprojT, d_out, flag);
}

// Round 3
// 397.266 us; speedup vs baseline: 1.0273x; 1.0102x over previous
//
#include <hip/hip_runtime.h>

#define DIN 2048
#define NH 16
#define DH 128
#define SEQ 2048
#define BB 2
#define N3 6144
#define MM 4096  // BB*SEQ

typedef __bf16 bf16;
typedef __attribute__((ext_vector_type(8))) __bf16 bf16x8;
typedef __attribute__((ext_vector_type(4))) __bf16 bf16x4;
typedef __attribute__((ext_vector_type(4))) float f32x4;

__device__ __forceinline__ f32x4 mfma16(bf16x8 a, bf16x8 b, f32x4 c) {
  return __builtin_amdgcn_mfma_f32_16x16x32_bf16(a, b, c, 0, 0, 0);
}

__device__ __forceinline__ void async16(const void* g, void* l) {
  __builtin_amdgcn_global_load_lds((const __attribute__((address_space(1))) void*)g,
                                   (__attribute__((address_space(3))) void*)l, 16, 0, 0);
}

// ---------------- dtype sniff ----------------
__global__ void sniff_k(const unsigned short* __restrict__ x, int* __restrict__ flag) {
  __shared__ int cnt;
  if (threadIdx.x == 0) cnt = 0;
  __syncthreads();
  unsigned short u = x[threadIdx.x * 2];
  int e = (u >> 7) & 0xff;
  if (e >= 108 && e <= 140) atomicAdd(&cnt, 1);
  __syncthreads();
  if (threadIdx.x == 0) *flag = (cnt >= 128) ? 1 : 0;
}

// ---------------- casts ----------------
__global__ __launch_bounds__(256) void cast_x_k(const void* __restrict__ in, bf16* __restrict__ out,
                                                const int* __restrict__ flag) {
  size_t i = ((size_t)blockIdx.x * 256 + threadIdx.x) * 8;
  if (*flag) {
    *(bf16x8*)(out + i) = *(const bf16x8*)((const bf16*)in + i);
  } else {
    const float* f = (const float*)in;
    bf16x8 v;
    for (int j = 0; j < 8; j++) v[j] = (bf16)f[i + j];
    *(bf16x8*)(out + i) = v;
  }
}

__global__ __launch_bounds__(256) void cast_wT_k(const void* __restrict__ in, bf16* __restrict__ out,
                                                 const int* __restrict__ flag, int R, int C) {
  __shared__ float t[32][33];
  int c0 = blockIdx.x * 32, r0 = blockIdx.y * 32;
  int tx = threadIdx.x & 31, ty = threadIdx.x >> 5;
  bool isb = *flag != 0;
  for (int j = 0; j < 4; j++) {
    int r = ty + j * 8;
    size_t idx = (size_t)(r0 + r) * C + c0 + tx;
    float v = isb ? (float)((const bf16*)in)[idx] : ((const float*)in)[idx];
    t[r][tx] = v;
  }
  __syncthreads();
  for (int j = 0; j < 4; j++) {
    int c = ty + j * 8;
    out[(size_t)(c0 + c) * R + r0 + tx] = (bf16)t[tx][c];
  }
}

// ---------------- qkv GEMM (round-0 proven: 128x128, BK=64, xor-swizzled chunks) ----
// 1536 blocks = 6.0 rounds -> no tail loss; 32 KiB LDS -> multi-block/CU covers
// the barrier drain. Measured 116.5 us (885 TF), at the m97-structure ceiling.
__global__ __launch_bounds__(256) void gemm_qkv_k(const bf16* __restrict__ A, const bf16* __restrict__ BT,
                                                  bf16* __restrict__ Qb, bf16* __restrict__ Kb,
                                                  bf16* __restrict__ Vb) {
  __shared__ __align__(16) bf16 As[128 * 64];
  __shared__ __align__(16) bf16 Bs[128 * 64];
  const int K = DIN;
  int m0 = blockIdx.y * 128, n0 = blockIdx.x * 128;
  int tid = threadIdx.x, w = tid >> 6, l = tid & 63;
  int l15 = l & 15, quad = l >> 4;
  int wm = (w & 1) * 64, wn = (w >> 1) * 64;
  f32x4 zero = {0.f, 0.f, 0.f, 0.f};
  f32x4 acc[4][4];
  for (int i = 0; i < 4; i++)
    for (int j = 0; j < 4; j++) acc[i][j] = zero;
  int gch = (l & 7) ^ (l >> 3);  // swizzled source chunk for this lane
  const bf16* Ag = A + (size_t)(m0 + w * 32 + (l >> 3)) * K + gch * 8;
  const bf16* Bg = BT + (size_t)(n0 + w * 32 + (l >> 3)) * K + gch * 8;
  bf16* AsW = As + w * 2048;  // wave stages rows w*32..+31 (4 KB)
  bf16* BsW = Bs + w * 2048;
  for (int k0 = 0; k0 < K; k0 += 64) {
    __syncthreads();
    for (int j = 0; j < 4; j++) async16(Ag + k0 + (size_t)j * 8 * K, AsW + j * 512);
    for (int j = 0; j < 4; j++) async16(Bg + k0 + (size_t)j * 8 * K, BsW + j * 512);
    __syncthreads();
    for (int kk = 0; kk < 2; kk++) {
      bf16x8 af[4], bfv[4];
      for (int i = 0; i < 4; i++)
        af[i] = *(const bf16x8*)&As[(wm + i * 16 + l15) * 64 + (((kk * 4 + quad) ^ (l15 & 7)) << 3)];
      for (int j = 0; j < 4; j++)
        bfv[j] = *(const bf16x8*)&Bs[(wn + j * 16 + l15) * 64 + (((kk * 4 + quad) ^ (l15 & 7)) << 3)];
      for (int i = 0; i < 4; i++)
        for (int j = 0; j < 4; j++) acc[i][j] = mfma16(af[i], bfv[j], acc[i][j]);
    }
  }
  for (int j = 0; j < 4; j++) {
    int col = n0 + wn + j * 16 + l15;
    int part = col >> 11, cw = col & 2047;
    int h = cw >> 7, d = cw & 127;
    bf16* dst = (part == 0) ? Qb : ((part == 1) ? Kb : Vb);
    for (int i = 0; i < 4; i++) {
      int mrow = m0 + wm + i * 16 + quad * 4;
      for (int r = 0; r < 4; r++) {
        int m = mrow + r;
        int b = m >> 11, s = m & 2047;
        int dd = (part == 1) ? (((((d >> 3) ^ (s & 7)) << 3)) | (d & 7)) : d;
        dst[(((size_t)(b * NH + h)) * SEQ + s) * DH + dd] = (bf16)acc[i][j][r];
      }
    }
  }
}

// ---------------- RoPE; Q gets DH^-0.5 * log2(e) folded in (scores in log2 domain) ----
__global__ __launch_bounds__(256) void rope_k(bf16* __restrict__ Qb, bf16* __restrict__ Kb) {
  int i = blockIdx.x * 256 + threadIdx.x;  // (bh, s, d2): 32*2048*64
  int d2 = i & 63;
  int s = (i >> 6) & 2047;
  int bh = i >> 17;
  int dl = 2 * d2;
  float invf = expf(-9.210340371976184f * (float)dl * (1.0f / 128.0f));
  float ang = (float)s * invf;
  float sn, cs;
  sincosf(ang, &sn, &cs);
  size_t row = ((size_t)bh * SEQ + s) * DH;
  const float scale = 0.08838834764831845f * 1.4426950408889634f;  // DH^-0.5 * log2(e)
  size_t qb = row + dl;
  float q1 = (float)Qb[qb], q2 = (float)Qb[qb + 1];
  Qb[qb] = (bf16)((q1 * cs - q2 * sn) * scale);
  Qb[qb + 1] = (bf16)((q1 * sn + q2 * cs) * scale);
  size_t kb = row + ((((dl >> 3) ^ (s & 7)) << 3) | (dl & 7));
  float k1 = (float)Kb[kb], k2 = (float)Kb[kb + 1];
  Kb[kb] = (bf16)(k1 * cs - k2 * sn);
  Kb[kb + 1] = (bf16)(k1 * sn + k2 * cs);
}

// ---------------- V transpose: (B,H,S,DH) -> (B,H,DH,S), swizzled within 64-col windows
__global__ __launch_bounds__(256) void transpose_v_k(const bf16* __restrict__ V, bf16* __restrict__ Vt) {
  __shared__ float t[32][33];
  int s0 = blockIdx.x * 32, d0 = blockIdx.y * 32;
  int bh = blockIdx.z;
  const bf16* Vp = V + (size_t)bh * SEQ * DH;
  bf16* Vo = Vt + (size_t)bh * DH * SEQ;
  int tx = threadIdx.x & 31, ty = threadIdx.x >> 5;
  for (int j = 0; j < 4; j++)
    t[ty + j * 8][tx] = (float)Vp[(size_t)(s0 + ty + j * 8) * DH + d0 + tx];
  __syncthreads();
  for (int j = 0; j < 4; j++) {
    int dh = d0 + ty + j * 8;
    int s = s0 + tx;
    int sl = s & 63;
    int col = (s & ~63) | ((((sl >> 3) ^ (dh & 7)) << 3) | (sl & 7));
    Vo[(size_t)dh * SEQ + col] = (bf16)t[tx][ty + j * 8];
  }
}

// ---------------- flash attention v5: counted-vmcnt pipeline ----------------
// Same structure as v4 (Q-tile 64 = 4 waves x 16 q-rows, K-tile 64 dbuf,
// 2 blocks/CU) but the per-iter __syncthreads (which drains vmcnt(0) on the
// loads issued THIS iter) is replaced by two raw barriers with counted vmcnt:
//   top:  vmcnt(4)  [own K(it) retired] ; barrier  -> all K(it) landed, and
//         all waves done reading buf^1 last iter (write-after-read safe)
//   stage K(it+1),V(it+1) -> buf^1
//   ... QK^T, softmax, P dance ...
//   vmcnt(8) [own V(it) retired; K/V(it+1) still in flight] ; barrier -> PV
// Last iter (nothing staged): vmcnt(0) instead of 8. Post-loop __syncthreads
// protects the half-boundary restage. Waits now target loads ~1 iter old
// instead of draining fresh ones.
__global__ __launch_bounds__(256, 2) void attn_k(const bf16* __restrict__ Qb, const bf16* __restrict__ Kb,
                                                 const bf16* __restrict__ Vt, bf16* __restrict__ Yb) {
  __shared__ __align__(16) bf16 Ks[2][64 * 128];
  __shared__ __align__(16) bf16 Vs[2][128 * 64];
  __shared__ __align__(16) bf16 Pl[4][16 * 76];
  int bh = blockIdx.x;
  int slot = blockIdx.y;
  int w = threadIdx.x >> 6, l = threadIdx.x & 63;
  int l15 = l & 15, quad = l >> 4;
  const bf16* Qp = Qb + (size_t)bh * SEQ * DH;
  const bf16* Kp = Kb + (size_t)bh * SEQ * DH;
  const bf16* Vp = Vt + (size_t)bh * DH * SEQ;
  int b = bh >> 4, h = bh & 15;
  f32x4 zero = {0.f, 0.f, 0.f, 0.f};
  bf16* P = &Pl[w][0];

  auto stage = [&](int it, int buf) {
    const char* gk = (const char*)Kp + (size_t)it * 16384 + w * 4096 + l * 16;
    char* lk = (char*)&Ks[buf][0] + w * 4096;
    for (int i = 0; i < 4; i++) async16(gk + i * 1024, lk + i * 1024);
    const char* gv = (const char*)Vp + (size_t)it * 128 + (size_t)(w * 32 + (l >> 3)) * (SEQ * 2) + (l & 7) * 16;
    char* lv = (char*)&Vs[buf][0] + w * 32 * 128;
    for (int i = 0; i < 4; i++) async16(gv + (size_t)i * 8 * (SEQ * 2), lv + i * 1024);
  };

  int tiles[2] = {31 - slot, slot};
  for (int half = 0; half < 2; half++) {
    int tile = tiles[half];
    int qw = tile * 64 + w * 16;  // this wave's 16 q rows
    bf16x8 qf[4];
    for (int kc = 0; kc < 4; kc++)
      qf[kc] = *(const bf16x8*)&Qp[(size_t)(qw + l15) * DH + kc * 32 + quad * 8];
    f32x4 o[8];
    for (int ns = 0; ns < 8; ns++) o[ns] = zero;
    float mprev = -1e30f, lsum = 0.f;
    int nkt = tile + 1;

    stage(0, 0);
    __syncthreads();
    for (int it = 0; it < nkt; it++) {
      int buf = it & 1;
      bool more = (it + 1 < nkt);
      // top gate: own K(it) retired (outstanding = K(it)4+V(it)4 -> 4), then
      // collective barrier: all waves' K(it) landed; buf^1 readers done.
      asm volatile("s_waitcnt vmcnt(4)" ::: "memory");
      __builtin_amdgcn_s_barrier();
      __builtin_amdgcn_sched_barrier(0);
      if (more) stage(it + 1, buf ^ 1);
      int k0 = it * 64;
      // S^T = K(row) x Q(col=l15=q)
      f32x4 st[4];
      for (int ns = 0; ns < 4; ns++) st[ns] = zero;
      for (int kc = 0; kc < 4; kc++)
        for (int ns = 0; ns < 4; ns++) {
          bf16x8 kf = *(const bf16x8*)&Ks[buf][(ns * 16 + l15) * 128 + (((kc * 4 + quad) ^ (l15 & 7)) << 3)];
          st[ns] = mfma16(kf, qf[kc], st[ns]);
        }
      int qq = qw + l15;
      if (k0 + 63 > qw) {  // diagonal tile: mask k > q
        for (int ns = 0; ns < 4; ns++) {
          int kk = k0 + ns * 16 + quad * 4;
          for (int r = 0; r < 4; r++)
            if (kk + r > qq) st[ns][r] = -1e30f;
        }
      }
      float pm = -1e30f;
      for (int ns = 0; ns < 4; ns++)
        for (int r = 0; r < 4; r++) pm = fmaxf(pm, st[ns][r]);
      pm = fmaxf(pm, __shfl_xor(pm, 16, 64));
      pm = fmaxf(pm, __shfl_xor(pm, 32, 64));
      float mnew = fmaxf(mprev, pm);
      float al = exp2f(mprev - mnew);
      mprev = mnew;
      float ps = 0.f;
      for (int ns = 0; ns < 4; ns++)
        for (int r = 0; r < 4; r++) {
          float e = exp2f(st[ns][r] - mnew);
          st[ns][r] = e;
          ps += e;
        }
      ps += __shfl_xor(ps, 16, 64);
      ps += __shfl_xor(ps, 32, 64);
      lsum = lsum * al + ps;
      for (int ns = 0; ns < 8; ns++) o[ns] *= al;
      // P^T (C-layout) -> P[q][k] rows: lane holds k=quad*4..+3 contiguous -> b64 writes
      for (int ns = 0; ns < 4; ns++) {
        bf16x4 pk;
        for (int r = 0; r < 4; r++) pk[r] = (bf16)st[ns][r];
        *(bf16x4*)&P[l15 * 76 + ns * 16 + quad * 4] = pk;
      }
      asm volatile("s_waitcnt lgkmcnt(0)" ::: "memory");
      bf16x8 pa[2];
      for (int kc = 0; kc < 2; kc++)
        pa[kc] = *(const bf16x8*)&P[l15 * 76 + kc * 32 + quad * 8];
      // PV gate: own V(it) retired (K/V(it+1) = 8 newer loads stay in flight),
      // then collective barrier -> all waves' V(it) landed.
      if (more) {
        asm volatile("s_waitcnt vmcnt(8)" ::: "memory");
      } else {
        asm volatile("s_waitcnt vmcnt(0)" ::: "memory");
      }
      __builtin_amdgcn_s_barrier();
      __builtin_amdgcn_sched_barrier(0);
      for (int ns = 0; ns < 8; ns++)
        for (int kc = 0; kc < 2; kc++) {
          bf16x8 vf = *(const bf16x8*)&Vs[buf][(ns * 16 + l15) * 64 + (((kc * 4 + quad) ^ (l15 & 7)) << 3)];
          o[ns] = mfma16(vf, pa[kc], o[ns]);  // O^T: col=l15=q
        }
    }
    __syncthreads();  // half-boundary: all reads done before next half's restage
    // epilogue: O^T col=l15=q, row(within ns)=quad*4+r -> d = ns*16+quad*4+r
    float inv = 1.0f / lsum;
    int q = qw + l15;
    size_t base = ((size_t)(b * SEQ + q)) * DIN + h * DH + quad * 4;
    for (int ns = 0; ns < 8; ns++) {
      bf16x4 pk;
      for (int r = 0; r < 4; r++) pk[r] = (bf16)(o[ns][r] * inv);
      *(bf16x4*)&Yb[base + ns * 16] = pk;
    }
  }
}

// ---------------- proj GEMM (BK=64, xor-swizzled LDS chunks) ----------------
__global__ __launch_bounds__(256) void gemm_proj_k(const bf16* __restrict__ A, const bf16* __restrict__ BT,
                                                   void* __restrict__ out, const int* __restrict__ flag) {
  __shared__ __align__(16) bf16 As[128 * 64];
  __shared__ __align__(16) bf16 Bs[128 * 64];
  const int K = DIN;
  int m0 = blockIdx.y * 128, n0 = blockIdx.x * 128;
  int tid = threadIdx.x, w = tid >> 6, l = tid & 63;
  int l15 = l & 15, quad = l >> 4;
  int wm = (w & 1) * 64, wn = (w >> 1) * 64;
  bool obf = *flag != 0;
  f32x4 zero = {0.f, 0.f, 0.f, 0.f};
  f32x4 acc[4][4];
  for (int i = 0; i < 4; i++)
    for (int j = 0; j < 4; j++) acc[i][j] = zero;
  int gch = (l & 7) ^ (l >> 3);
  const bf16* Ag = A + (size_t)(m0 + w * 32 + (l >> 3)) * K + gch * 8;
  const bf16* Bg = BT + (size_t)(n0 + w * 32 + (l >> 3)) * K + gch * 8;
  bf16* AsW = As + w * 2048;
  bf16* BsW = Bs + w * 2048;
  for (int k0 = 0; k0 < K; k0 += 64) {
    __syncthreads();
    for (int j = 0; j < 4; j++) async16(Ag + k0 + (size_t)j * 8 * K, AsW + j * 512);
    for (int j = 0; j < 4; j++) async16(Bg + k0 + (size_t)j * 8 * K, BsW + j * 512);
    __syncthreads();
    for (int kk = 0; kk < 2; kk++) {
      bf16x8 af[4], bfv[4];
      for (int i = 0; i < 4; i++)
        af[i] = *(const bf16x8*)&As[(wm + i * 16 + l15) * 64 + (((kk * 4 + quad) ^ (l15 & 7)) << 3)];
      for (int j = 0; j < 4; j++)
        bfv[j] = *(const bf16x8*)&Bs[(wn + j * 16 + l15) * 64 + (((kk * 4 + quad) ^ (l15 & 7)) << 3)];
      for (int i = 0; i < 4; i++)
        for (int j = 0; j < 4; j++) acc[i][j] = mfma16(af[i], bfv[j], acc[i][j]);
    }
  }
  for (int j = 0; j < 4; j++) {
    int col = n0 + wn + j * 16 + l15;
    for (int i = 0; i < 4; i++) {
      int mrow = m0 + wm + i * 16 + quad * 4;
      for (int r = 0; r < 4; r++) {
        size_t idx = (size_t)(mrow + r) * DIN + col;
        float v = acc[i][j][r];
        if (obf)
          ((bf16*)out)[idx] = (bf16)v;
        else
          ((float*)out)[idx] = v;
      }
    }
  }
}

extern "C" void kernel_launch(void* const* d_in, const int* in_sizes, int n_in,
                              void* d_out, int out_size, void* d_ws, size_t ws_size,
                              hipStream_t stream) {
  char* ws = (char*)d_ws;
  int* flag = (int*)ws;
  bf16* Xb = (bf16*)(ws + 256);                                  // 16 MiB, aliased with Yb
  bf16* WqkvT = (bf16*)(ws + 256 + 16777216);                    // 24 MiB
  bf16* WprojT = (bf16*)(ws + 256 + 16777216 + 25165824);        // 8 MiB
  bf16* Qb = (bf16*)(ws + 256 + 16777216 + 25165824 + 8388608);  // 16 MiB each
  bf16* Kb = Qb + (size_t)MM * DIN;
  bf16* Vb = Kb + (size_t)MM * DIN;
  bf16* Vt = Vb + (size_t)MM * DIN;
  bf16* Yb = Xb;  // Xb dead after gemm_qkv

  sniff_k<<<1, 256, 0, stream>>>((const unsigned short*)d_in[0], flag);
  cast_x_k<<<4096, 256, 0, stream>>>(d_in[0], Xb, flag);
  cast_wT_k<<<dim3(192, 64), 256, 0, stream>>>(d_in[1], WqkvT, flag, DIN, N3);
  cast_wT_k<<<dim3(64, 64), 256, 0, stream>>>(d_in[2], WprojT, flag, DIN, DIN);
  gemm_qkv_k<<<dim3(48, 32), 256, 0, stream>>>(Xb, WqkvT, Qb, Kb, Vb);
  rope_k<<<16384, 256, 0, stream>>>(Qb, Kb);
  transpose_v_k<<<dim3(64, 4, 32), 256, 0, stream>>>(Vb, Vt);
  attn_k<<<dim3(32, 16), 256, 0, stream>>>(Qb, Kb, Vt, Yb);
  gemm_proj_k<<<dim3(16, 32), 256, 0, stream>>>(Yb, WprojT, d_out, flag);
}

// Round 4
// 395.689 us; speedup vs baseline: 1.0314x; 1.0040x over previous
//
#include <hip/hip_runtime.h>

#define DIN 2048
#define NH 16
#define DH 128
#define SEQ 2048
#define BB 2
#define N3 6144
#define MM 4096  // BB*SEQ

typedef __bf16 bf16;
typedef __attribute__((ext_vector_type(8))) __bf16 bf16x8;
typedef __attribute__((ext_vector_type(4))) __bf16 bf16x4;
typedef __attribute__((ext_vector_type(2))) __bf16 bf16x2;
typedef __attribute__((ext_vector_type(4))) float f32x4;

__device__ __forceinline__ f32x4 mfma16(bf16x8 a, bf16x8 b, f32x4 c) {
  return __builtin_amdgcn_mfma_f32_16x16x32_bf16(a, b, c, 0, 0, 0);
}

__device__ __forceinline__ void async16(const void* g, void* l) {
  __builtin_amdgcn_global_load_lds((const __attribute__((address_space(1))) void*)g,
                                   (__attribute__((address_space(3))) void*)l, 16, 0, 0);
}

// ---------------- dtype sniff ----------------
__global__ void sniff_k(const unsigned short* __restrict__ x, int* __restrict__ flag) {
  __shared__ int cnt;
  if (threadIdx.x == 0) cnt = 0;
  __syncthreads();
  unsigned short u = x[threadIdx.x * 2];
  int e = (u >> 7) & 0xff;
  if (e >= 108 && e <= 140) atomicAdd(&cnt, 1);
  __syncthreads();
  if (threadIdx.x == 0) *flag = (cnt >= 128) ? 1 : 0;
}

// ---------------- casts ----------------
__global__ __launch_bounds__(256) void cast_x_k(const void* __restrict__ in, bf16* __restrict__ out,
                                                const int* __restrict__ flag) {
  size_t i = ((size_t)blockIdx.x * 256 + threadIdx.x) * 8;
  if (*flag) {
    *(bf16x8*)(out + i) = *(const bf16x8*)((const bf16*)in + i);
  } else {
    const float* f = (const float*)in;
    bf16x8 v;
    for (int j = 0; j < 8; j++) v[j] = (bf16)f[i + j];
    *(bf16x8*)(out + i) = v;
  }
}

// 32x32 transpose tile; write phase emits 4B bf16x2 pairs (2x wider than scalar).
__global__ __launch_bounds__(256) void cast_wT_k(const void* __restrict__ in, bf16* __restrict__ out,
                                                 const int* __restrict__ flag, int R, int C) {
  __shared__ float t[32][33];
  int c0 = blockIdx.x * 32, r0 = blockIdx.y * 32;
  int tx = threadIdx.x & 31, ty = threadIdx.x >> 5;
  bool isb = *flag != 0;
  for (int j = 0; j < 4; j++) {
    int r = ty + j * 8;
    size_t idx = (size_t)(r0 + r) * C + c0 + tx;
    float v = isb ? (float)((const bf16*)in)[idx] : ((const float*)in)[idx];
    t[r][tx] = v;
  }
  __syncthreads();
  int tx8 = threadIdx.x & 15;  // row-pair index: rows 2*tx8, 2*tx8+1
  int cy = threadIdx.x >> 4;   // 0..15
  for (int j = 0; j < 2; j++) {
    int c = cy + j * 16;
    bf16x2 v;
    v[0] = (bf16)t[2 * tx8][c];
    v[1] = (bf16)t[2 * tx8 + 1][c];
    *(bf16x2*)&out[(size_t)(c0 + c) * R + r0 + 2 * tx8] = v;
  }
}

// ---------------- qkv GEMM (proven 128x128, BK=64, xor-swizzled chunks) ----
// 1536 blocks = 6.0 rounds -> no tail loss; 32 KiB LDS -> multi-block/CU covers
// the barrier drain. Measured 116.5-118 us (~885 TF), the m97-structure ceiling.
// Epilogue now ALSO performs the V transpose (writes Vt directly, bf16x4) --
// s is the register-fast axis so transposed stores are wider than the old Vb
// scalar stores; kills the separate transpose_v kernel + 34 MB round-trip.
__global__ __launch_bounds__(256) void gemm_qkv_k(const bf16* __restrict__ A, const bf16* __restrict__ BT,
                                                  bf16* __restrict__ Qb, bf16* __restrict__ Kb,
                                                  bf16* __restrict__ Vt) {
  __shared__ __align__(16) bf16 As[128 * 64];
  __shared__ __align__(16) bf16 Bs[128 * 64];
  const int K = DIN;
  int m0 = blockIdx.y * 128, n0 = blockIdx.x * 128;
  int tid = threadIdx.x, w = tid >> 6, l = tid & 63;
  int l15 = l & 15, quad = l >> 4;
  int wm = (w & 1) * 64, wn = (w >> 1) * 64;
  f32x4 zero = {0.f, 0.f, 0.f, 0.f};
  f32x4 acc[4][4];
  for (int i = 0; i < 4; i++)
    for (int j = 0; j < 4; j++) acc[i][j] = zero;
  int gch = (l & 7) ^ (l >> 3);  // swizzled source chunk for this lane
  const bf16* Ag = A + (size_t)(m0 + w * 32 + (l >> 3)) * K + gch * 8;
  const bf16* Bg = BT + (size_t)(n0 + w * 32 + (l >> 3)) * K + gch * 8;
  bf16* AsW = As + w * 2048;  // wave stages rows w*32..+31 (4 KB)
  bf16* BsW = Bs + w * 2048;
  for (int k0 = 0; k0 < K; k0 += 64) {
    __syncthreads();
    for (int j = 0; j < 4; j++) async16(Ag + k0 + (size_t)j * 8 * K, AsW + j * 512);
    for (int j = 0; j < 4; j++) async16(Bg + k0 + (size_t)j * 8 * K, BsW + j * 512);
    __syncthreads();
    for (int kk = 0; kk < 2; kk++) {
      bf16x8 af[4], bfv[4];
      for (int i = 0; i < 4; i++)
        af[i] = *(const bf16x8*)&As[(wm + i * 16 + l15) * 64 + (((kk * 4 + quad) ^ (l15 & 7)) << 3)];
      for (int j = 0; j < 4; j++)
        bfv[j] = *(const bf16x8*)&Bs[(wn + j * 16 + l15) * 64 + (((kk * 4 + quad) ^ (l15 & 7)) << 3)];
      for (int i = 0; i < 4; i++)
        for (int j = 0; j < 4; j++) acc[i][j] = mfma16(af[i], bfv[j], acc[i][j]);
    }
  }
  for (int j = 0; j < 4; j++) {
    int col = n0 + wn + j * 16 + l15;
    int part = col >> 11, cw = col & 2047;
    int h = cw >> 7, d = cw & 127;
    if (part < 2) {
      bf16* dst = (part == 0) ? Qb : Kb;
      for (int i = 0; i < 4; i++) {
        int mrow = m0 + wm + i * 16 + quad * 4;
        for (int r = 0; r < 4; r++) {
          int m = mrow + r;
          int b = m >> 11, s = m & 2047;
          // K rows carry the 16B-chunk xor swizzle consumed by attn's DMA staging
          int dd = (part == 1) ? ((((d >> 3) ^ (s & 7)) << 3) | (d & 7)) : d;
          dst[(((size_t)(b * NH + h)) * SEQ + s) * DH + dd] = (bf16)acc[i][j][r];
        }
      }
    } else {
      // V: transposed+swizzled direct write (B,H,DH,S layout, 64-col windows).
      // Within an r-run of 4: same b, same s&~63, same (s>>3)&7 -> bf16x4 store.
      for (int i = 0; i < 4; i++) {
        int mrow = m0 + wm + i * 16 + quad * 4;
        int b = mrow >> 11, s = mrow & 2047;
        int scol = (s & ~63) | (((((s >> 3) & 7) ^ (d & 7)) << 3) | (s & 7));
        bf16x4 pk;
        for (int r = 0; r < 4; r++) pk[r] = (bf16)acc[i][j][r];
        *(bf16x4*)&Vt[((size_t)(b * NH + h) * DH + d) * SEQ + scol] = pk;
      }
    }
  }
}

// ---------------- RoPE; Q gets DH^-0.5 * log2(e) folded in (scores in log2 domain) ----
__global__ __launch_bounds__(256) void rope_k(bf16* __restrict__ Qb, bf16* __restrict__ Kb) {
  int i = blockIdx.x * 256 + threadIdx.x;  // (bh, s, d2): 32*2048*64
  int d2 = i & 63;
  int s = (i >> 6) & 2047;
  int bh = i >> 17;
  int dl = 2 * d2;
  float invf = expf(-9.210340371976184f * (float)dl * (1.0f / 128.0f));
  float ang = (float)s * invf;
  float sn, cs;
  sincosf(ang, &sn, &cs);
  size_t row = ((size_t)bh * SEQ + s) * DH;
  const float scale = 0.08838834764831845f * 1.4426950408889634f;  // DH^-0.5 * log2(e)
  size_t qb = row + dl;
  float q1 = (float)Qb[qb], q2 = (float)Qb[qb + 1];
  Qb[qb] = (bf16)((q1 * cs - q2 * sn) * scale);
  Qb[qb + 1] = (bf16)((q1 * sn + q2 * cs) * scale);
  size_t kb = row + ((((dl >> 3) ^ (s & 7)) << 3) | (dl & 7));
  float k1 = (float)Kb[kb], k2 = (float)Kb[kb + 1];
  Kb[kb] = (bf16)(k1 * cs - k2 * sn);
  Kb[kb + 1] = (bf16)(k1 * sn + k2 * cs);
}

// ---------------- flash attention v5: counted-vmcnt pipeline + setprio ----------------
// Q-tile 64 (4 waves x 16 q-rows), K-tile 64 dbuf, 2 blocks/CU. Counted-vmcnt
// gates (round 3, race-free): top vmcnt(4)+barrier gates K(it); PV vmcnt(8)
// +barrier gates V(it) while K/V(it+1) stay in flight. setprio(1) wraps both
// MFMA clusters (T5 probe; predicted neutral on this lockstep structure).
__global__ __launch_bounds__(256, 2) void attn_k(const bf16* __restrict__ Qb, const bf16* __restrict__ Kb,
                                                 const bf16* __restrict__ Vt, bf16* __restrict__ Yb) {
  __shared__ __align__(16) bf16 Ks[2][64 * 128];
  __shared__ __align__(16) bf16 Vs[2][128 * 64];
  __shared__ __align__(16) bf16 Pl[4][16 * 76];
  int bh = blockIdx.x;
  int slot = blockIdx.y;
  int w = threadIdx.x >> 6, l = threadIdx.x & 63;
  int l15 = l & 15, quad = l >> 4;
  const bf16* Qp = Qb + (size_t)bh * SEQ * DH;
  const bf16* Kp = Kb + (size_t)bh * SEQ * DH;
  const bf16* Vp = Vt + (size_t)bh * DH * SEQ;
  int b = bh >> 4, h = bh & 15;
  f32x4 zero = {0.f, 0.f, 0.f, 0.f};
  bf16* P = &Pl[w][0];

  auto stage = [&](int it, int buf) {
    const char* gk = (const char*)Kp + (size_t)it * 16384 + w * 4096 + l * 16;
    char* lk = (char*)&Ks[buf][0] + w * 4096;
    for (int i = 0; i < 4; i++) async16(gk + i * 1024, lk + i * 1024);
    const char* gv = (const char*)Vp + (size_t)it * 128 + (size_t)(w * 32 + (l >> 3)) * (SEQ * 2) + (l & 7) * 16;
    char* lv = (char*)&Vs[buf][0] + w * 32 * 128;
    for (int i = 0; i < 4; i++) async16(gv + (size_t)i * 8 * (SEQ * 2), lv + i * 1024);
  };

  int tiles[2] = {31 - slot, slot};
  for (int half = 0; half < 2; half++) {
    int tile = tiles[half];
    int qw = tile * 64 + w * 16;  // this wave's 16 q rows
    bf16x8 qf[4];
    for (int kc = 0; kc < 4; kc++)
      qf[kc] = *(const bf16x8*)&Qp[(size_t)(qw + l15) * DH + kc * 32 + quad * 8];
    f32x4 o[8];
    for (int ns = 0; ns < 8; ns++) o[ns] = zero;
    float mprev = -1e30f, lsum = 0.f;
    int nkt = tile + 1;

    stage(0, 0);
    __syncthreads();
    for (int it = 0; it < nkt; it++) {
      int buf = it & 1;
      bool more = (it + 1 < nkt);
      // top gate: own K(it) retired (outstanding = K(it)4+V(it)4 -> 4), then
      // collective barrier: all waves' K(it) landed; buf^1 readers done.
      asm volatile("s_waitcnt vmcnt(4)" ::: "memory");
      __builtin_amdgcn_s_barrier();
      __builtin_amdgcn_sched_barrier(0);
      if (more) stage(it + 1, buf ^ 1);
      int k0 = it * 64;
      // S^T = K(row) x Q(col=l15=q)
      f32x4 st[4];
      for (int ns = 0; ns < 4; ns++) st[ns] = zero;
      __builtin_amdgcn_s_setprio(1);
      for (int kc = 0; kc < 4; kc++)
        for (int ns = 0; ns < 4; ns++) {
          bf16x8 kf = *(const bf16x8*)&Ks[buf][(ns * 16 + l15) * 128 + (((kc * 4 + quad) ^ (l15 & 7)) << 3)];
          st[ns] = mfma16(kf, qf[kc], st[ns]);
        }
      __builtin_amdgcn_s_setprio(0);
      int qq = qw + l15;
      if (k0 + 63 > qw) {  // diagonal tile: mask k > q
        for (int ns = 0; ns < 4; ns++) {
          int kk = k0 + ns * 16 + quad * 4;
          for (int r = 0; r < 4; r++)
            if (kk + r > qq) st[ns][r] = -1e30f;
        }
      }
      float pm = -1e30f;
      for (int ns = 0; ns < 4; ns++)
        for (int r = 0; r < 4; r++) pm = fmaxf(pm, st[ns][r]);
      pm = fmaxf(pm, __shfl_xor(pm, 16, 64));
      pm = fmaxf(pm, __shfl_xor(pm, 32, 64));
      float mnew = fmaxf(mprev, pm);
      float al = exp2f(mprev - mnew);
      mprev = mnew;
      float ps = 0.f;
      for (int ns = 0; ns < 4; ns++)
        for (int r = 0; r < 4; r++) {
          float e = exp2f(st[ns][r] - mnew);
          st[ns][r] = e;
          ps += e;
        }
      ps += __shfl_xor(ps, 16, 64);
      ps += __shfl_xor(ps, 32, 64);
      lsum = lsum * al + ps;
      for (int ns = 0; ns < 8; ns++) o[ns] *= al;
      // P^T (C-layout) -> P[q][k] rows: lane holds k=quad*4..+3 contiguous -> b64 writes
      for (int ns = 0; ns < 4; ns++) {
        bf16x4 pk;
        for (int r = 0; r < 4; r++) pk[r] = (bf16)st[ns][r];
        *(bf16x4*)&P[l15 * 76 + ns * 16 + quad * 4] = pk;
      }
      asm volatile("s_waitcnt lgkmcnt(0)" ::: "memory");
      bf16x8 pa[2];
      for (int kc = 0; kc < 2; kc++)
        pa[kc] = *(const bf16x8*)&P[l15 * 76 + kc * 32 + quad * 8];
      // PV gate: own V(it) retired (K/V(it+1) = 8 newer loads stay in flight),
      // then collective barrier -> all waves' V(it) landed.
      if (more) {
        asm volatile("s_waitcnt vmcnt(8)" ::: "memory");
      } else {
        asm volatile("s_waitcnt vmcnt(0)" ::: "memory");
      }
      __builtin_amdgcn_s_barrier();
      __builtin_amdgcn_sched_barrier(0);
      __builtin_amdgcn_s_setprio(1);
      for (int ns = 0; ns < 8; ns++)
        for (int kc = 0; kc < 2; kc++) {
          bf16x8 vf = *(const bf16x8*)&Vs[buf][(ns * 16 + l15) * 64 + (((kc * 4 + quad) ^ (l15 & 7)) << 3)];
          o[ns] = mfma16(vf, pa[kc], o[ns]);  // O^T: col=l15=q
        }
      __builtin_amdgcn_s_setprio(0);
    }
    __syncthreads();  // half-boundary: all reads done before next half's restage
    // epilogue: O^T col=l15=q, row(within ns)=quad*4+r -> d = ns*16+quad*4+r
    float inv = 1.0f / lsum;
    int q = qw + l15;
    size_t base = ((size_t)(b * SEQ + q)) * DIN + h * DH + quad * 4;
    for (int ns = 0; ns < 8; ns++) {
      bf16x4 pk;
      for (int r = 0; r < 4; r++) pk[r] = (bf16)(o[ns][r] * inv);
      *(bf16x4*)&Yb[base + ns * 16] = pk;
    }
  }
}

// ---------------- proj GEMM (BK=64, xor-swizzled LDS chunks) ----------------
__global__ __launch_bounds__(256) void gemm_proj_k(const bf16* __restrict__ A, const bf16* __restrict__ BT,
                                                   void* __restrict__ out, const int* __restrict__ flag) {
  __shared__ __align__(16) bf16 As[128 * 64];
  __shared__ __align__(16) bf16 Bs[128 * 64];
  const int K = DIN;
  int m0 = blockIdx.y * 128, n0 = blockIdx.x * 128;
  int tid = threadIdx.x, w = tid >> 6, l = tid & 63;
  int l15 = l & 15, quad = l >> 4;
  int wm = (w & 1) * 64, wn = (w >> 1) * 64;
  bool obf = *flag != 0;
  f32x4 zero = {0.f, 0.f, 0.f, 0.f};
  f32x4 acc[4][4];
  for (int i = 0; i < 4; i++)
    for (int j = 0; j < 4; j++) acc[i][j] = zero;
  int gch = (l & 7) ^ (l >> 3);
  const bf16* Ag = A + (size_t)(m0 + w * 32 + (l >> 3)) * K + gch * 8;
  const bf16* Bg = BT + (size_t)(n0 + w * 32 + (l >> 3)) * K + gch * 8;
  bf16* AsW = As + w * 2048;
  bf16* BsW = Bs + w * 2048;
  for (int k0 = 0; k0 < K; k0 += 64) {
    __syncthreads();
    for (int j = 0; j < 4; j++) async16(Ag + k0 + (size_t)j * 8 * K, AsW + j * 512);
    for (int j = 0; j < 4; j++) async16(Bg + k0 + (size_t)j * 8 * K, BsW + j * 512);
    __syncthreads();
    for (int kk = 0; kk < 2; kk++) {
      bf16x8 af[4], bfv[4];
      for (int i = 0; i < 4; i++)
        af[i] = *(const bf16x8*)&As[(wm + i * 16 + l15) * 64 + (((kk * 4 + quad) ^ (l15 & 7)) << 3)];
      for (int j = 0; j < 4; j++)
        bfv[j] = *(const bf16x8*)&Bs[(wn + j * 16 + l15) * 64 + (((kk * 4 + quad) ^ (l15 & 7)) << 3)];
      for (int i = 0; i < 4; i++)
        for (int j = 0; j < 4; j++) acc[i][j] = mfma16(af[i], bfv[j], acc[i][j]);
    }
  }
  for (int j = 0; j < 4; j++) {
    int col = n0 + wn + j * 16 + l15;
    for (int i = 0; i < 4; i++) {
      int mrow = m0 + wm + i * 16 + quad * 4;
      for (int r = 0; r < 4; r++) {
        size_t idx = (size_t)(mrow + r) * DIN + col;
        float v = acc[i][j][r];
        if (obf)
          ((bf16*)out)[idx] = (bf16)v;
        else
          ((float*)out)[idx] = v;
      }
    }
  }
}

extern "C" void kernel_launch(void* const* d_in, const int* in_sizes, int n_in,
                              void* d_out, int out_size, void* d_ws, size_t ws_size,
                              hipStream_t stream) {
  char* ws = (char*)d_ws;
  int* flag = (int*)ws;
  bf16* Xb = (bf16*)(ws + 256);                                  // 16 MiB, aliased with Yb
  bf16* WqkvT = (bf16*)(ws + 256 + 16777216);                    // 24 MiB
  bf16* WprojT = (bf16*)(ws + 256 + 16777216 + 25165824);        // 8 MiB
  bf16* Qb = (bf16*)(ws + 256 + 16777216 + 25165824 + 8388608);  // 16 MiB each
  bf16* Kb = Qb + (size_t)MM * DIN;
  bf16* Vb = Kb + (size_t)MM * DIN;  // unused (V written transposed directly)
  bf16* Vt = Vb + (size_t)MM * DIN;
  bf16* Yb = Xb;  // Xb dead after gemm_qkv

  sniff_k<<<1, 256, 0, stream>>>((const unsigned short*)d_in[0], flag);
  cast_x_k<<<4096, 256, 0, stream>>>(d_in[0], Xb, flag);
  cast_wT_k<<<dim3(192, 64), 256, 0, stream>>>(d_in[1], WqkvT, flag, DIN, N3);
  cast_wT_k<<<dim3(64, 64), 256, 0, stream>>>(d_in[2], WprojT, flag, DIN, DIN);
  gemm_qkv_k<<<dim3(48, 32), 256, 0, stream>>>(Xb, WqkvT, Qb, Kb, Vt);
  rope_k<<<16384, 256, 0, stream>>>(Qb, Kb);
  attn_k<<<dim3(32, 16), 256, 0, stream>>>(Qb, Kb, Vt, Yb);
  gemm_proj_k<<<dim3(16, 32), 256, 0, stream>>>(Yb, WprojT, d_out, flag);
}